// Round 1
// 904.333 us; speedup vs baseline: 1.0807x; 1.0807x over previous
//
#include <hip/hip_runtime.h>
#include <cstdint>
#include <cstddef>

typedef __bf16 bf16_t;
typedef __bf16 bf16x8 __attribute__((ext_vector_type(8)));
typedef __bf16 bf16x4 __attribute__((ext_vector_type(4)));
typedef float floatx4 __attribute__((ext_vector_type(4)));

// ---------------------------------------------------------------- helpers
__device__ __forceinline__ void async16(const bf16_t* g, bf16_t* l) {
  __builtin_amdgcn_global_load_lds(
      (const __attribute__((address_space(1))) unsigned int*)g,
      (__attribute__((address_space(3))) unsigned int*)l, 16, 0, 0);
}

// Barrier that drains ONLY lgkmcnt (LDS) — leaves prefetch global loads
// in flight across the barrier (compiler's __syncthreads drains vmcnt(0)).
__device__ __forceinline__ void barrier_lds() {
  asm volatile("s_waitcnt lgkmcnt(0)\n\ts_barrier" ::: "memory");
}

__device__ __forceinline__ float siluf(float x) { return x / (1.f + __expf(-x)); }

#define MFMA16(a, b, c) __builtin_amdgcn_mfma_f32_16x16x32_bf16(a, b, c, 0, 0, 0)

// ---------------------------------------------------------------- fp32 -> bf16
__global__ __launch_bounds__(256) void k_cvt(const float* __restrict__ in,
                                             bf16_t* __restrict__ out, int n4) {
  int i = blockIdx.x * 256 + threadIdx.x;
  if (i >= n4) return;
  const float4 f = ((const float4*)in)[i];
  bf16x4 r;
  r[0] = (bf16_t)f.x; r[1] = (bf16_t)f.y; r[2] = (bf16_t)f.z; r[3] = (bf16_t)f.w;
  ((bf16x4*)out)[i] = r;
}

// W_b rows 0..31, W_a rows 32..63, zeros 64..127
__global__ __launch_bounds__(256) void k_build_wba(const float* __restrict__ wb,
                                                   const float* __restrict__ wa,
                                                   bf16_t* __restrict__ out) {
  int i = blockIdx.x * 256 + threadIdx.x;
  int e = i * 4;
  int row = e >> 11;
  int col = e & 2047;
  float4 f = make_float4(0.f, 0.f, 0.f, 0.f);
  if (row < 32)      f = *(const float4*)&wb[row * 2048 + col];
  else if (row < 64) f = *(const float4*)&wa[(row - 32) * 2048 + col];
  bf16x4 r;
  r[0] = (bf16_t)f.x; r[1] = (bf16_t)f.y; r[2] = (bf16_t)f.z; r[3] = (bf16_t)f.w;
  *(bf16x4*)&out[e] = r;
}

// ---------------------------------------------------------------- GEMM (m97-style)
// Kept for the small N=128 (ba) GEMM and the N=2048 out-GEMM (256-tile grid
// would only fill 128 CUs there).
template<bool OUT_BF16>
__global__ __launch_bounds__(256) void gemm_bt(const bf16_t* __restrict__ A,
                                               const bf16_t* __restrict__ B,
                                               void* __restrict__ Cout,
                                               int M, int N, int K) {
  __shared__ __align__(16) bf16_t As[4096];
  __shared__ __align__(16) bf16_t Bs[4096];
  const int tid  = threadIdx.x;
  const int lane = tid & 63;
  const int wave = tid >> 6;
  const int quad = lane >> 4;
  const int l16  = lane & 15;
  const int wr   = (wave >> 1) * 64;
  const int wc   = (wave & 1) * 64;
  const int m0   = blockIdx.y * 128;
  const int n0   = blockIdx.x * 128;
  const int ra   = tid >> 2;
  const int ca   = (tid & 3) * 8;

  const bf16_t* gA = A + (size_t)(m0 + ra) * K + ca;
  const bf16_t* gB = B + (size_t)(n0 + ra) * K + ca;
  bf16_t* lA = &As[tid * 8];
  bf16_t* lB = &Bs[tid * 8];

  floatx4 acc[4][4] = {};

  for (int k0 = 0; k0 < K; k0 += 32) {
    __syncthreads();
    async16(gA + k0, lA);
    async16(gA + k0 + (size_t)64 * K, lA + 2048);
    async16(gB + k0, lB);
    async16(gB + k0 + (size_t)64 * K, lB + 2048);
    __syncthreads();
    bf16x8 af[4], bfr[4];
#pragma unroll
    for (int i = 0; i < 4; ++i) {
      af[i]  = *(const bf16x8*)&As[(wr + i * 16 + l16) * 32 + quad * 8];
      bfr[i] = *(const bf16x8*)&Bs[(wc + i * 16 + l16) * 32 + quad * 8];
    }
#pragma unroll
    for (int mi = 0; mi < 4; ++mi)
#pragma unroll
      for (int ni = 0; ni < 4; ++ni)
        acc[mi][ni] = MFMA16(af[mi], bfr[ni], acc[mi][ni]);
  }

#pragma unroll
  for (int mi = 0; mi < 4; ++mi) {
#pragma unroll
    for (int ni = 0; ni < 4; ++ni) {
      const int row = m0 + wr + mi * 16 + quad * 4;
      const int col = n0 + wc + ni * 16 + l16;
#pragma unroll
      for (int r = 0; r < 4; ++r) {
        if (OUT_BF16)
          ((bf16_t*)Cout)[(size_t)(row + r) * N + col] = (bf16_t)acc[mi][ni][r];
        else
          ((float*)Cout)[(size_t)(row + r) * N + col] = acc[mi][ni][r];
      }
    }
  }
}

// ---------------------------------------------------------------- GEMM 256x256 deep-pipelined
// T2 swizzle + T3/T4 counted vmcnt + T5 setprio (regime-gated combo, §5.5).
// BM=BN=256, BK=32. 512 threads = 8 waves (2M x 4N), per-wave 128x64 output
// (8 M-frags x 4 N-frags, 16x16x32 bf16 MFMA). 4-deep LDS K-tile ring:
// 4 x (A[256][32] + B[256][32]) bf16 = 128 KB dynamic LDS -> 1 block/CU.
//
// Schedule per K-tile U (2 phases, 16 MFMA each):
//   ph0: ds_read A(mh=0) x4 + B x4 | stage A(U+3) (2 gload_lds) | bar |
//        prio1 16xMFMA prio0 | bar
//   ph1: ds_read A(mh=1) x4        | stage B(U+3) (2 gload_lds) |
//        vmcnt(8) | bar | prio1 16xMFMA prio0 | bar
// Staging target buf (U+3)&3 == (U-1)&3: its reads finished at U-1's last
// barrier -> race-free. vmcnt(8) leaves K-tiles U+2,U+3 (4 loads each) in
// flight, guarantees U+1 landed: counted, never 0 in main loop (T4).
// Tail drains 8 -> 4 -> 0. Raw s_barrier only (no vmcnt drain at barriers).
//
// LDS swizzle (both-sides, rule #21): desired LDS[swz(b)] = G[b] with
// swz(b) = b ^ (((b>>7)&3)<<4)  (involution; source bits 7-8 = row bits 1-2,
// target bits 4-5 = 16B slot). gload_lds writes linearly (base + lane*16B),
// so the GLOBAL source slot is pre-swizzled: slot_src = (lane&3)^((lane>>3)&3)
// (valid since every issue covers 16 aligned rows). ds_read applies the same
// XOR: elem ^= ((row>>1)&3)<<3. Turns the 16-way stride-64B read conflict
// into 2-way (free per m136).
template<bool OUT_BF16>
__global__ __launch_bounds__(512, 1) void gemm256(const bf16_t* __restrict__ A,
                                                  const bf16_t* __restrict__ B,
                                                  void* __restrict__ Cout,
                                                  int M, int N, int K) {
  extern __shared__ __align__(16) bf16_t sm[];
  const int tid  = threadIdx.x;
  const int lane = tid & 63;
  const int wave = tid >> 6;   // 0..7
  const int quad = lane >> 4;
  const int l16  = lane & 15;
  const int wm   = wave >> 2;  // 0..1  M half (128 rows)
  const int wn   = wave & 3;   // 0..3  N quarter (64 cols)

  // bijective XCD swizzle (caller guarantees nwg % 8 == 0): each XCD gets a
  // contiguous run of blocks -> consecutive bx share the A-panel in its L2.
  const int gx  = (int)gridDim.x;
  const int nwg = gx * (int)gridDim.y;
  const int id  = (int)blockIdx.y * gx + (int)blockIdx.x;
  const int cpx = nwg >> 3;
  const int sw  = (id & 7) * cpx + (id >> 3);
  const int m0  = (sw / gx) * 256;
  const int n0  = (sw % gx) * 256;

  // ---- staging addresses (each issue: 64 lanes x 16B = 16 rows x 64B)
  const int lr    = lane >> 2;                       // row within issue
  const int lslot = (lane & 3) ^ ((lane >> 3) & 3);  // pre-swizzled 16B slot
  const bf16_t* gA = A + (size_t)(m0 + wave * 32 + lr) * K + lslot * 8;
  const bf16_t* gB = B + (size_t)(n0 + wave * 32 + lr) * K + lslot * 8;
  // LDS (elements): buffer u at u*16384; A at +0, B at +8192. Row = 32 elems.
  const int ldsA0 = wave * 1024 + lane * 8;
  const int ldsB0 = 8192 + wave * 1024 + lane * 8;

#define STG_A(u, kt) {                                          \
    bf16_t* la = sm + (u) * 16384 + ldsA0;                      \
    const bf16_t* ga = gA + (size_t)(kt) * 32;                  \
    async16(ga, la);                                            \
    async16(ga + (size_t)16 * K, la + 512); }
#define STG_B(u, kt) {                                          \
    bf16_t* lb = sm + (u) * 16384 + ldsB0;                      \
    const bf16_t* gb = gB + (size_t)(kt) * 32;                  \
    async16(gb, lb);                                            \
    async16(gb + (size_t)16 * K, lb + 512); }

  // ---- fragment read offsets (swizzled; 16B-aligned by construction)
  int offA[8], offB[4];
#pragma unroll
  for (int i = 0; i < 8; ++i) {
    int ra = wm * 128 + i * 16 + l16;
    offA[i] = (ra * 32 + quad * 8) ^ (((ra >> 1) & 3) << 3);
  }
#pragma unroll
  for (int i = 0; i < 4; ++i) {
    int rb = wn * 64 + i * 16 + l16;
    offB[i] = 8192 + ((rb * 32 + quad * 8) ^ (((rb >> 1) & 3) << 3));
  }

  floatx4 acc[8][4] = {};
  const int KT = K >> 5;  // caller guarantees KT >= 4

  // ---- prologue: stage K-tiles 0,1,2 (12 loads); land K0, keep 8 in flight
  STG_A(0, 0); STG_B(0, 0);
  STG_A(1, 1); STG_B(1, 1);
  STG_A(2, 2); STG_B(2, 2);
  asm volatile("s_waitcnt vmcnt(8)" ::: "memory");
  asm volatile("s_barrier" ::: "memory");

  for (int U = 0; U < KT; ++U) {
    const int bu = U & 3;
    const bf16_t* sb = sm + bu * 16384;
    const int un = U + 3;
    const int tu = un & 3;
    bf16x8 af[4], bfr[4];

    // ---- phase 0: quadrant mh=0; stage A(U+3)
#pragma unroll
    for (int i = 0; i < 4; ++i) {
      af[i]  = *(const bf16x8*)&sb[offA[i]];
      bfr[i] = *(const bf16x8*)&sb[offB[i]];
    }
    if (un < KT) STG_A(tu, un);
    asm volatile("s_barrier" ::: "memory");
    __builtin_amdgcn_s_setprio(1);
#pragma unroll
    for (int mi = 0; mi < 4; ++mi)
#pragma unroll
      for (int ni = 0; ni < 4; ++ni)
        acc[mi][ni] = MFMA16(af[mi], bfr[ni], acc[mi][ni]);
    __builtin_amdgcn_s_setprio(0);
    asm volatile("s_barrier" ::: "memory");

    // ---- phase 1: quadrant mh=1; stage B(U+3); counted vmcnt
#pragma unroll
    for (int i = 0; i < 4; ++i) af[i] = *(const bf16x8*)&sb[offA[4 + i]];
    if (un < KT) STG_B(tu, un);
    if (un < KT)         asm volatile("s_waitcnt vmcnt(8)" ::: "memory");
    else if (U + 2 < KT) asm volatile("s_waitcnt vmcnt(4)" ::: "memory");
    else                 asm volatile("s_waitcnt vmcnt(0)" ::: "memory");
    asm volatile("s_barrier" ::: "memory");
    __builtin_amdgcn_s_setprio(1);
#pragma unroll
    for (int mi = 0; mi < 4; ++mi)
#pragma unroll
      for (int ni = 0; ni < 4; ++ni)
        acc[4 + mi][ni] = MFMA16(af[mi], bfr[ni], acc[4 + mi][ni]);
    __builtin_amdgcn_s_setprio(0);
    asm volatile("s_barrier" ::: "memory");
  }
#undef STG_A
#undef STG_B

  // ---- epilogue (same proven C/D mapping as gemm_bt)
#pragma unroll
  for (int mi = 0; mi < 8; ++mi) {
#pragma unroll
    for (int ni = 0; ni < 4; ++ni) {
      const int row = m0 + wm * 128 + mi * 16 + quad * 4;
      const int col = n0 + wn * 64 + ni * 16 + l16;
#pragma unroll
      for (int r = 0; r < 4; ++r) {
        if (OUT_BF16)
          ((bf16_t*)Cout)[(size_t)(row + r) * N + col] = (bf16_t)acc[mi][ni][r];
        else
          ((float*)Cout)[(size_t)(row + r) * N + col] = acc[mi][ni][r];
      }
    }
  }
}

// ---------------------------------------------------------------- beta / g ([h][t] layout)
__global__ __launch_bounds__(256) void k_betag(const float* __restrict__ cba,
                                               const float* __restrict__ A_log,
                                               const float* __restrict__ dtb,
                                               float* __restrict__ beta_t,
                                               float* __restrict__ g_t) {
  int i = blockIdx.x * 256 + threadIdx.x;  // T*32
  int t = i >> 5, h = i & 31;
  float b = cba[t * 128 + h];
  float a = cba[t * 128 + 32 + h];
  beta_t[h * 4096 + t] = 1.f / (1.f + __expf(-b));
  float x = a + dtb[h];
  float sp = (x > 20.f) ? x : log1pf(__expf(x));
  g_t[h * 4096 + t] = -__expf(A_log[h]) * sp;
}

// ---------------------------------------------------------------- conv4 + silu + l2norm
// 1-wave blocks, 8 tokens per block via sliding window. grid (64 groups, 512).
__global__ __launch_bounds__(64) void k_conv(const bf16_t* __restrict__ mixed,
                                             const float* __restrict__ cw,
                                             bf16_t* __restrict__ qo,
                                             bf16_t* __restrict__ ko,
                                             bf16_t* __restrict__ vo) {
  const int grp = blockIdx.x;
  const int t0 = blockIdx.y * 8;
  const int l = threadIdx.x;
  const int c0 = grp * 128 + l;
  const int c1 = c0 + 64;
  const float4 w0 = *(const float4*)&cw[c0 * 4];
  const float4 w1 = *(const float4*)&cw[c1 * 4];
  float h0[3], h1[3];
#pragma unroll
  for (int j = 0; j < 3; ++j) {
    int tt = t0 - 3 + j;
    h0[j] = (tt >= 0) ? (float)mixed[(size_t)tt * 8192 + c0] : 0.f;
    h1[j] = (tt >= 0) ? (float)mixed[(size_t)tt * 8192 + c1] : 0.f;
  }
#pragma unroll
  for (int i = 0; i < 8; ++i) {
    const int t = t0 + i;
    float x0 = (float)mixed[(size_t)t * 8192 + c0];
    float x1 = (float)mixed[(size_t)t * 8192 + c1];
    float a0 = w0.x * h0[0] + w0.y * h0[1] + w0.z * h0[2] + w0.w * x0;
    float a1 = w1.x * h1[0] + w1.y * h1[1] + w1.z * h1[2] + w1.w * x1;
    h0[0] = h0[1]; h0[1] = h0[2]; h0[2] = x0;
    h1[0] = h1[1]; h1[1] = h1[2]; h1[2] = x1;
    float v0 = siluf(a0), v1 = siluf(a1);
    if (grp < 32) {
      float s = v0 * v0 + v1 * v1;
#pragma unroll
      for (int m = 1; m < 64; m <<= 1) s += __shfl_xor(s, m);
      float r = rsqrtf(s + 1e-6f);
      if (grp < 16) {
        bf16_t* q = qo + ((size_t)t * 16 + grp) * 128;
        q[l]      = (bf16_t)(v0 * r * 0.08838834764831845f);  // DK^-0.5 folded
        q[l + 64] = (bf16_t)(v1 * r * 0.08838834764831845f);
      } else {
        bf16_t* k = ko + ((size_t)t * 16 + grp - 16) * 128;
        k[l]      = (bf16_t)(v0 * r);
        k[l + 64] = (bf16_t)(v1 * r);
      }
    } else {
      bf16_t* v = vo + ((size_t)t * 32 + grp - 32) * 128;
      v[l]      = (bf16_t)v0;
      v[l + 64] = (bf16_t)v1;
    }
  }
}

// ---------------------------------------------------------------- k_prep
// grid = 32 heads x 64 chunks (blockIdx.x = c*32 + h). 256 threads.
// Solves (I+C)[Vt | W] = [beta*V | beta*A*K]; writes VtT ([dv][t] transposed!),
// W' = -W ([t][dk]), M, K^T, smalls.
__global__ __launch_bounds__(256, 2) void k_prep(
    const bf16_t* __restrict__ qg, const bf16_t* __restrict__ kg,
    const bf16_t* __restrict__ vg,
    const float* __restrict__ bb_t, const float* __restrict__ gb_t,
    bf16_t* __restrict__ Vt, bf16_t* __restrict__ Wlo, bf16_t* __restrict__ Whi,
    bf16_t* __restrict__ Mout, bf16_t* __restrict__ kt, float* __restrict__ smalls) {
  const int c = blockIdx.x >> 5;
  const int h = blockIdx.x & 31;
  const int kh = h >> 1;
  const int t0 = c * 64;
  const int tid = threadIdx.x, lane = tid & 63, wave = tid >> 6;
  const int quad = lane >> 4, l16 = lane & 15;

  __shared__ __align__(16) bf16_t lsKQ[2][64][136];
  __shared__ float lsC[64][68];
  __shared__ float lsG[64], lsA[64], lsSc[64], lsBeta[64];

  {
    const int r = tid >> 2, s0 = (tid & 3) * 32;
    const bf16_t* kr = kg + ((size_t)(t0 + r) * 16 + kh) * 128 + s0;
    const bf16_t* qr = qg + ((size_t)(t0 + r) * 16 + kh) * 128 + s0;
#pragma unroll
    for (int j = 0; j < 4; ++j) {
      *(uint4*)&lsKQ[0][r][s0 + j * 8] = *(const uint4*)&kr[j * 8];
      *(uint4*)&lsKQ[1][r][s0 + j * 8] = *(const uint4*)&qr[j * 8];
    }
  }
  if (wave == 0) {
    float gv = gb_t[(size_t)h * 4096 + t0 + lane];
#pragma unroll
    for (int off = 1; off < 64; off <<= 1) {
      float n = __shfl_up(gv, off);
      if (lane >= off) gv += n;
    }
    float GL = __shfl(gv, 63);
    lsG[lane] = gv;
    lsA[lane] = __expf(gv);
    lsSc[lane] = __expf(GL - gv);
    lsBeta[lane] = bb_t[(size_t)h * 4096 + t0 + lane];
  }
  __syncthreads();

  const int mr = (wave >> 1) * 32, nr = (wave & 1) * 32;
  floatx4 ak[2][2] = {}, aq[2][2] = {};
  if (wave != 1) {
#pragma unroll
    for (int ks = 0; ks < 4; ++ks) {
      bf16x8 yf[2], xk[2], xq[2];
#pragma unroll
      for (int i = 0; i < 2; ++i) {
        yf[i] = *(const bf16x8*)&lsKQ[0][nr + i * 16 + l16][ks * 32 + quad * 8];
        xk[i] = *(const bf16x8*)&lsKQ[0][mr + i * 16 + l16][ks * 32 + quad * 8];
        xq[i] = *(const bf16x8*)&lsKQ[1][mr + i * 16 + l16][ks * 32 + quad * 8];
      }
#pragma unroll
      for (int i = 0; i < 2; ++i)
#pragma unroll
        for (int j = 0; j < 2; ++j) {
          ak[i][j] = MFMA16(xk[i], yf[j], ak[i][j]);
          aq[i][j] = MFMA16(xq[i], yf[j], aq[i][j]);
        }
    }
  }
  bf16_t* Mb = Mout + (size_t)(h * 64 + c) * 4096;
#pragma unroll
  for (int i = 0; i < 2; ++i)
#pragma unroll
    for (int j = 0; j < 2; ++j)
#pragma unroll
      for (int r = 0; r < 4; ++r) {
        int t = mr + i * 16 + quad * 4 + r;
        int s = nr + j * 16 + l16;
        float e = __expf(lsG[t] - lsG[s]);
        float cv = (s < t) ? lsBeta[t] * e * ak[i][j][r] : 0.f;
        float mv = (s <= t) ? e * aq[i][j][r] : 0.f;
        if (wave != 1) lsC[t][s] = cv;
        Mb[t * 64 + s] = (bf16_t)mv;
      }
  __syncthreads();

  // forward substitution: thread <-> column. cols 0..127: V, 128..255: W-rhs
  const int col = tid & 127;
  const bool isW = tid >= 128;
  float vals[64];
#pragma unroll
  for (int t = 0; t < 64; ++t) {
    float b;
    if (!isW) b = (float)vg[((size_t)(t0 + t) * 32 + h) * 128 + col];
    else      b = lsA[t] * (float)lsKQ[0][t][col];
    vals[t] = lsBeta[t] * b;
  }
#pragma unroll
  for (int t = 1; t < 64; ++t) {
    float acc = vals[t];
#pragma unroll
    for (int s4 = 0; s4 <= (t - 1) >> 2; ++s4) {
      float4 cv = *(const float4*)&lsC[t][s4 * 4];
      acc -= cv.x * vals[s4 * 4 + 0];
      acc -= cv.y * vals[s4 * 4 + 1];
      acc -= cv.z * vals[s4 * 4 + 2];
      acc -= cv.w * vals[s4 * 4 + 3];
    }
    vals[t] = acc;
  }

  // V columns: direct transposed write (VtT[dv][t], contiguous in t)
  if (!isW) {
    bf16_t* vd = Vt + (size_t)(h * 64 + c) * 8192 + (size_t)col * 64;
#pragma unroll
    for (int j = 0; j < 16; ++j) {
      bf16x4 p;
      p[0] = (bf16_t)vals[j * 4 + 0];
      p[1] = (bf16_t)vals[j * 4 + 1];
      p[2] = (bf16_t)vals[j * 4 + 2];
      p[3] = (bf16_t)vals[j * 4 + 3];
      *(bf16x4*)&vd[j * 4] = p;
    }
  } else {
#pragma unroll
    for (int t = 0; t < 64; ++t) vals[t] = -vals[t];  // W' = -W
  }

  // K^T for the chain
  if ((h & 1) == 0) {
    const int dk = tid >> 1, sh = (tid & 1) * 32;
    bf16_t* kd = kt + (size_t)(c * 16 + kh) * 8192 + (size_t)dk * 64 + sh;
#pragma unroll
    for (int j4 = 0; j4 < 4; ++j4) {
      bf16x8 v;
#pragma unroll
      for (int e = 0; e < 8; ++e) v[e] = lsKQ[0][sh + j4 * 8 + e][dk];
      *(bf16x8*)&kd[j4 * 8] = v;
    }
  }
  if (tid < 64) {
    float* sm = smalls + (size_t)(h * 64 + c) * 128;
    sm[tid] = lsA[tid];
    sm[64 + tid] = lsSc[tid];
  }
  __syncthreads();

  // transpose W half via LDS (overlay lsKQ), pitch 272
  bf16_t* lsT = &lsKQ[0][0][0];
  if (isW) {
#pragma unroll
    for (int t = 0; t < 64; ++t) lsT[t * 272 + tid] = (bf16_t)vals[t];
  }
  __syncthreads();

  // cooperative vectorized W' write: [t][dk 128]
  {
    const int r = tid >> 2, part = tid & 3;
    const bf16_t* src = &lsT[r * 272 + 128 + part * 32];
    bf16_t* Wb = (h < 16 ? Wlo : Whi) + (size_t)((h & 15) * 64 + c) * 8192 + r * 128 + part * 32;
#pragma unroll
    for (int j = 0; j < 4; ++j)
      *(uint4*)&Wb[j * 8] = *(const uint4*)&src[j * 8];
  }
}

// ---------------------------------------------------------------- chain prefetch
__device__ __forceinline__ void chain_prefetch(
    int c2, int wave, int l16, int quad, int trow, int dv0, int kh,
    const bf16_t* __restrict__ Wbase, const bf16_t* __restrict__ Vbase,
    const bf16_t* __restrict__ Mbase, const bf16_t* __restrict__ qg,
    const bf16_t* __restrict__ ktg, const float* __restrict__ Sbase,
    bf16x8 nW[4], bf16x8 nQ[4], bf16x8 nK[4], bf16x8 nM[2],
    bf16x4 nV[4], float4& nA, float4& nSc, float& nAL) {
  const bf16_t* Wn = Wbase + (size_t)c2 * 8192;
  const bf16_t* Vn = Vbase + (size_t)c2 * 8192;
  const bf16_t* Qn = qg + ((size_t)(c2 * 64 + wave * 16 + l16) * 16 + kh) * 128;
  const bf16_t* Kn = ktg + (size_t)(c2 * 16 + kh) * 8192;
  const bf16_t* Mn = Mbase + (size_t)c2 * 4096 + (wave * 16 + l16) * 64;
  const float* sm = Sbase + (size_t)c2 * 128;
#pragma unroll
  for (int ks = 0; ks < 4; ++ks) {
    nW[ks] = *(const bf16x8*)&Wn[(size_t)(wave * 16 + l16) * 128 + ks * 32 + quad * 8];
    nQ[ks] = *(const bf16x8*)&Qn[ks * 32 + quad * 8];
    nK[ks] = *(const bf16x8*)&Kn[(size_t)((wave + 4 * (ks >> 1)) * 16 + l16) * 64 + (ks & 1) * 32 + quad * 8];
  }
#pragma unroll
  for (int ks = 0; ks < 2; ++ks) nM[ks] = *(const bf16x8*)&Mn[ks * 32 + quad * 8];
#pragma unroll
  for (int tn = 0; tn < 4; ++tn)
    nV[tn] = *(const bf16x4*)&Vn[(size_t)(dv0 + tn * 16 + l16) * 64 + trow];
  nA = *(const float4*)&sm[trow];
  nSc = *(const float4*)&sm[64 + trow];
  nAL = sm[63];
}

// ---------------------------------------------------------------- k_chain
// grid = 64: blockIdx = half*32 + h (same-head halves share an XCD L2).
// Per chunk: X = Vt + W'.S ; o = A*(Q.S) + M.X ; S' = aL*S + K^T.(sc*X)
// All streams register-prefetched one chunk ahead; lgkm-only barriers keep
// prefetch loads in flight across barriers. bS kept in regs for P0+P1.
__global__ __launch_bounds__(256, 1) void k_chain(
    const bf16_t* __restrict__ qg, const bf16_t* __restrict__ VtT,
    const bf16_t* __restrict__ Wlo, const bf16_t* __restrict__ Whi,
    const bf16_t* __restrict__ Mg, const bf16_t* __restrict__ ktg,
    const float* __restrict__ smalls, bf16_t* __restrict__ o) {
  const int h = blockIdx.x & 31;
  const int dv0 = (blockIdx.x >> 5) * 64;
  const int kh = h >> 1;
  const int tid = threadIdx.x, lane = tid & 63, wave = tid >> 6;
  const int quad = lane >> 4, l16 = lane & 15;
  const int trow = wave * 16 + quad * 4;

  __shared__ __align__(16) bf16_t lsXT[64][72];
  __shared__ __align__(16) bf16_t lsXbT[64][72];
  __shared__ __align__(16) bf16_t lsS[64][136];

  const bf16_t* Wbase = (h < 16 ? Wlo : Whi) + (size_t)(h & 15) * 64 * 8192;
  const bf16_t* Vbase = VtT + (size_t)h * 64 * 8192;
  const bf16_t* Mbase = Mg + (size_t)h * 64 * 4096;
  const float*  Sbase = smalls + (size_t)h * 64 * 128;

  floatx4 sacc[2][4] = {};
  for (int i = tid; i < 64 * 136; i += 256) (&lsS[0][0])[i] = (bf16_t)0.f;

  bf16x8 nW[4], nQ[4], nK[4], nM[2];
  bf16x4 nV[4];
  float4 nA, nSc;
  float nAL;
  chain_prefetch(0, wave, l16, quad, trow, dv0, kh, Wbase, Vbase, Mbase, qg, ktg,
                 Sbase, nW, nQ, nK, nM, nV, nA, nSc, nAL);
  __syncthreads();

  for (int cc = 0; cc < 64; ++cc) {
    const int t0 = cc * 64;
    bf16x8 cW[4], cQ[4], cK[4], cM[2];
    float cV[16];
    float4 cA = nA, cSc = nSc;
    float cAL = nAL;
#pragma unroll
    for (int ks = 0; ks < 4; ++ks) { cW[ks] = nW[ks]; cQ[ks] = nQ[ks]; cK[ks] = nK[ks]; }
    cM[0] = nM[0]; cM[1] = nM[1];
#pragma unroll
    for (int tn = 0; tn < 4; ++tn)
#pragma unroll
      for (int r = 0; r < 4; ++r) cV[tn * 4 + r] = (float)nV[tn][r];

    if (cc + 1 < 64)
      chain_prefetch(cc + 1, wave, l16, quad, trow, dv0, kh, Wbase, Vbase, Mbase,
                     qg, ktg, Sbase, nW, nQ, nK, nM, nV, nA, nSc, nAL);

    // ---- P0: X = Vt + W'.S  (bS kept for P1)
    bf16x8 bS[4][4];
#pragma unroll
    for (int ks = 0; ks < 4; ++ks)
#pragma unroll
      for (int tn = 0; tn < 4; ++tn)
        bS[ks][tn] = *(const bf16x8*)&lsS[tn * 16 + l16][ks * 32 + quad * 8];
    floatx4 xacc[4];
#pragma unroll
    for (int tn = 0; tn < 4; ++tn)
#pragma unroll
      for (int r = 0; r < 4; ++r) xacc[tn][r] = cV[tn * 4 + r];
#pragma unroll
    for (int ks = 0; ks < 4; ++ks)
#pragma unroll
      for (int tn = 0; tn < 4; ++tn)
        xacc[tn] = MFMA16(cW[ks], bS[ks][tn], xacc[tn]);
#pragma unroll
    for (int tn = 0; tn < 4; ++tn) {
      bf16x4 px, pb;
#pragma unroll
      for (int r = 0; r < 4; ++r) {
        px[r] = (bf16_t)xacc[tn][r];
        pb[r] = (bf16_t)(xacc[tn][r] * ((const float*)&cSc)[r]);
      }
      *(bf16x4*)&lsXT[tn * 16 + l16][trow] = px;
      *(bf16x4*)&lsXbT[tn * 16 + l16][trow] = pb;
    }
    barrier_lds();  // B1: X ready; lsS reads done

    // ---- P1: o = A*(Q.S) + M.X ; S' = aL*S + K^T.(sc*X)
    floatx4 qacc[4] = {};
#pragma unroll
    for (int ks = 0; ks < 4; ++ks)
#pragma unroll
      for (int tn = 0; tn < 4; ++tn)
        qacc[tn] = MFMA16(cQ[ks], bS[ks][tn], qacc[tn]);
#pragma unroll
    for (int tn = 0; tn < 4; ++tn)
#pragma unroll
      for (int r = 0; r < 4; ++r) qacc[tn][r] *= ((const float*)&cA)[r];
#pragma unroll
    for (int ks = 0; ks < 2; ++ks)
#pragma unroll
      for (int tn = 0; tn < 4; ++tn) {
        bf16x8 bX = *(const bf16x8*)&lsXT[tn * 16 + l16][ks * 32 + quad * 8];
        qacc[tn] = MFMA16(cM[ks], bX, qacc[tn]);
      }
#pragma unroll
    for (int tn = 0; tn < 4; ++tn)
#pragma unroll
      for (int r = 0; r < 4; ++r)
        o[((size_t)(t0 + trow + r) * 32 + h) * 128 + dv0 + tn * 16 + l16] =
            (bf16_t)qacc[tn][r];
#pragma unroll
    for (int mh = 0; mh < 2; ++mh)
#pragma unroll
      for (int tn = 0; tn < 4; ++tn)
#pragma unroll
        for (int r = 0; r < 4; ++r) sacc[mh][tn][r] *= cAL;
#pragma unroll
    for (int ks = 0; ks < 2; ++ks) {
      bf16x8 bXb[4];
#pragma unroll
      for (int tn = 0; tn < 4; ++tn)
        bXb[tn] = *(const bf16x8*)&lsXbT[tn * 16 + l16][ks * 32 + quad * 8];
#pragma unroll
      for (int mh = 0; mh < 2; ++mh)
#pragma unroll
        for (int tn = 0; tn < 4; ++tn)
          sacc[mh][tn] = MFMA16(cK[mh * 2 + ks], bXb[tn], sacc[mh][tn]);
    }
    // ---- P2: refresh bf16 state (safe: all lsS reads happened before B1)
#pragma unroll
    for (int mh = 0; mh < 2; ++mh)
#pragma unroll
      for (int tn = 0; tn < 4; ++tn) {
        bf16x4 ps;
#pragma unroll
        for (int r = 0; r < 4; ++r) ps[r] = (bf16_t)sacc[mh][tn][r];
        *(bf16x4*)&lsS[tn * 16 + l16][(wave + 4 * mh) * 16 + quad * 4] = ps;
      }
    barrier_lds();  // B2: S visible; lsXT/lsXbT reads done before next P0 write
  }
}

// ---------------------------------------------------------------- RMSNorm * silu(z)
// block 256 = 4 waves, one (t,h) row per wave. grid 32768.
__global__ __launch_bounds__(256) void k_gate(const bf16_t* __restrict__ o,
                                              const bf16_t* __restrict__ z,
                                              const float* __restrict__ nw,
                                              bf16_t* __restrict__ y) {
  const int row = blockIdx.x * 4 + (threadIdx.x >> 6);  // t*32+h
  const int l = threadIdx.x & 63;
  const bf16_t* orow = o + (size_t)row * 128;
  float o0 = (float)orow[l], o1 = (float)orow[l + 64];
  float s = o0 * o0 + o1 * o1;
#pragma unroll
  for (int m = 1; m < 64; m <<= 1) s += __shfl_xor(s, m);
  float r = rsqrtf(s * (1.f / 128.f) + 1e-6f);
  const bf16_t* zrow = z + (size_t)row * 128;
  float z0 = (float)zrow[l], z1 = (float)zrow[l + 64];
  bf16_t* yrow = y + (size_t)row * 128;
  yrow[l]      = (bf16_t)(o0 * r * nw[l] * siluf(z0));
  yrow[l + 64] = (bf16_t)(o1 * r * nw[l + 64] * siluf(z1));
}

// ---------------------------------------------------------------- launch
extern "C" void kernel_launch(void* const* d_in, const int* in_sizes, int n_in,
                              void* d_out, int out_size, void* d_ws, size_t ws_size,
                              hipStream_t stream) {
  const float* hidden = (const float*)d_in[0];
  const float* W_qkv  = (const float*)d_in[1];
  const float* W_z    = (const float*)d_in[2];
  const float* W_b    = (const float*)d_in[3];
  const float* W_a    = (const float*)d_in[4];
  const float* conv_w = (const float*)d_in[5];
  const float* dt_b   = (const float*)d_in[6];
  const float* A_log  = (const float*)d_in[7];
  const float* norm_w = (const float*)d_in[8];
  const float* W_out  = (const float*)d_in[9];
  float* out = (float*)d_out;

  // 128KB dynamic LDS for gemm256 (above the 64KB static default; gfx950 has
  // 160KB/CU). One-time attribute bump; not a stream op (graph-capture safe).
  static int gemm_attr_done = 0;
  if (!gemm_attr_done) {
    hipFuncSetAttribute(reinterpret_cast<const void*>(&gemm256<true>),
                        hipFuncAttributeMaxDynamicSharedMemorySize, 131072);
    hipFuncSetAttribute(reinterpret_cast<const void*>(&gemm256<false>),
                        hipFuncAttributeMaxDynamicSharedMemorySize, 131072);
    gemm_attr_done = 1;
  }

  char* w = (char*)d_ws;
  const size_t MB = 1024 * 1024;
  bf16_t* hs    = (bf16_t*)(w + 0 * MB);     // 16MB; after ba-GEMM -> W_lo
  bf16_t* Wlo   = hs;
  bf16_t* wqkv  = (bf16_t*)(w + 16 * MB);    // 32MB; -> VtT (prep) -> ybuf (gate)
  bf16_t* Vtb   = wqkv;
  bf16_t* ybuf  = wqkv;
  bf16_t* wz    = (bf16_t*)(w + 48 * MB);    // 16MB; -> W_hi
  bf16_t* Whi   = wz;
  bf16_t* wout  = (bf16_t*)(w + 64 * MB);    // 16MB (live till end)
  bf16_t* wba   = (bf16_t*)(w + 80 * MB);    // 0.5MB
  bf16_t* mixed = (bf16_t*)(w + 81 * MB);    // 64MB (qkv out); after conv:
  bf16_t* obuf  = mixed;                     //   [obuf bf16 32MB @81]
  bf16_t* Mbuf  = (bf16_t*)(w + 113 * MB);   //   [M 16MB @113]
  bf16_t* ktb   = (bf16_t*)(w + 129 * MB);   //   [K^T 16MB @129]
  bf16_t* zbuf  = (bf16_t*)(w + 145 * MB);   // 32MB
  float*  cba   = (float*)(w + 177 * MB);    // 2MB; after betag -> smalls (1MB)
  float*  smalls= cba;
  bf16_t* qb    = (bf16_t*)(w + 179 * MB);   // 16MB
  bf16_t* kb    = (bf16_t*)(w + 195 * MB);   // 16MB
  bf16_t* vb    = (bf16_t*)(w + 211 * MB);   // 32MB
  float*  betab = (float*)(w + 243 * MB);    // 0.5MB [h][t]
  float*  gbuf  = (float*)(w + 243 * MB + 512 * 1024);  // 0.5MB [h][t]

  k_cvt<<<8192, 256, 0, stream>>>(hidden, hs, 2097152);
  k_cvt<<<16384, 256, 0, stream>>>(W_qkv, wqkv, 4194304);
  k_cvt<<<8192, 256, 0, stream>>>(W_z, wz, 2097152);
  k_cvt<<<8192, 256, 0, stream>>>(W_out, wout, 2097152);
  k_build_wba<<<256, 256, 0, stream>>>(W_b, W_a, wba);

  // 256-tile deep-pipelined GEMMs (grid %8==0 for the XCD swizzle; K%32==0)
  gemm256<true><<<dim3(32, 16), 512, 131072, stream>>>(hs, wqkv, mixed, 4096, 8192, 2048);
  gemm256<true><<<dim3(16, 16), 512, 131072, stream>>>(hs, wz, zbuf, 4096, 4096, 2048);
  gemm_bt<false><<<dim3(1, 32), 256, 0, stream>>>(hs, wba, cba, 4096, 128, 2048);
  k_betag<<<512, 256, 0, stream>>>(cba, A_log, dt_b, betab, gbuf);

  k_conv<<<dim3(64, 512), 64, 0, stream>>>(mixed, conv_w, qb, kb, vb);

  k_prep<<<2048, 256, 0, stream>>>(qb, kb, vb, betab, gbuf,
                                   Vtb, Wlo, Whi, Mbuf, ktb, smalls);
  k_chain<<<64, 256, 0, stream>>>(qb, Vtb, Wlo, Whi, Mbuf, ktb, smalls, obuf);

  k_gate<<<32768, 256, 0, stream>>>(obuf, zbuf, norm_w, ybuf);
  // N=2048 -> only 128 blocks at 256-tile; keep the 128-tile kernel here.
  gemm_bt<false><<<dim3(16, 32), 256, 0, stream>>>(ybuf, wout, out, 4096, 2048, 4096);
}